// Round 12
// baseline (135.093 us; speedup 1.0000x reference)
//
#include <hip/hip_runtime.h>
#include <math.h>

#define NQ 14
#define NL 4
#define NS (1 << NQ)      // 16384 amplitudes
#define NT 1024           // threads per block
#define APT (NS / NT)     // 16 amps per thread

struct c32 { float x, y; };
__device__ __forceinline__ c32 cmul(c32 a, c32 b) { return {a.x*b.x - a.y*b.y, a.x*b.y + a.y*b.x}; }
__device__ __forceinline__ c32 cadd(c32 a, c32 b) { return {a.x + b.x, a.y + b.y}; }

// phase (p1*p2) applied to f — 2 cmuls on main VALU (no trans pipe)
__device__ __forceinline__ c32 phase_mul(float2 p1, float2 p2, float2 f) {
    c32 ph = { p1.x*p2.x - p1.y*p2.y, p1.x*p2.y + p1.y*p2.x };
    return { ph.x*f.x - ph.y*f.y, ph.x*f.y + ph.y*f.x };
}

// Butterfly gates; U reloaded per call (2x float4) to cap live registers.
__device__ __forceinline__ void gate8(c32* v, const float* U, const int s) {
    float4 u0 = *(const float4*)U;
    float4 u1 = *(const float4*)(U + 4);
    c32 a00={u0.x,u0.y}, a01={u0.z,u0.w}, a10={u1.x,u1.y}, a11={u1.z,u1.w};
    #pragma unroll
    for (int k = 0; k < 8; ++k) {
        if (k & s) continue;
        c32 A = v[k], B = v[k | s];
        v[k]     = cadd(cmul(a00, A), cmul(a01, B));
        v[k | s] = cadd(cmul(a10, A), cmul(a11, B));
    }
}

// Slot k holds logical element k^swbits: role-swapped U'[i][j]=U[i^sw][j^sw]
// (r6/r7/r11-verified pattern).
__device__ __forceinline__ void gate8sw(c32* v, const float* U, const int s, const int sw) {
    float4 u0 = *(const float4*)U;
    float4 u1 = *(const float4*)(U + 4);
    c32 n00={u0.x,u0.y}, n01={u0.z,u0.w}, n10={u1.x,u1.y}, n11={u1.z,u1.w};
    c32 a00 = sw ? n11 : n00;
    c32 a01 = sw ? n10 : n01;
    c32 a10 = sw ? n01 : n10;
    c32 a11 = sw ? n00 : n11;
    #pragma unroll
    for (int k = 0; k < 8; ++k) {
        if (k & s) continue;
        c32 A = v[k], B = v[k | s];
        v[k]     = cadd(cmul(a00, A), cmul(a01, B));
        v[k | s] = cadd(cmul(a10, A), cmul(a11, B));
    }
}

__device__ __forceinline__ void gate4sw(c32* v, const float* U, const int s, const int sw) {
    float4 u0 = *(const float4*)U;
    float4 u1 = *(const float4*)(U + 4);
    c32 n00={u0.x,u0.y}, n01={u0.z,u0.w}, n10={u1.x,u1.y}, n11={u1.z,u1.w};
    c32 a00 = sw ? n11 : n00;
    c32 a01 = sw ? n10 : n01;
    c32 a10 = sw ? n01 : n10;
    c32 a11 = sw ? n00 : n11;
    #pragma unroll
    for (int k = 0; k < 4; ++k) {
        if (k & s) continue;
        c32 A = v[k], B = v[k | s];
        v[k]     = cadd(cmul(a00, A), cmul(a01, B));
        v[k | s] = cadd(cmul(a10, A), cmul(a11, B));
    }
}

__global__ __launch_bounds__(NT) __attribute__((amdgpu_waves_per_eu(4, 4)))
void qc_kernel(const float* __restrict__ x,
               const float* __restrict__ prx,
               const float* __restrict__ pry,
               const float* __restrict__ prz,
               const float* __restrict__ pent,
               float* __restrict__ out)
{
    __shared__ float2 st[NS];            // 128 KB state, natural order
    __shared__ float  Um[NL][NQ][8];     // fused Rz*Ry*Rx per (layer,qubit)
    __shared__ float2 tloc[NL][128];     // entangle phase (cos,sin), bits 0..6
    __shared__ float2 thic[NL][64];      // bits 7..12
    __shared__ float  encc[NQ], encs[NQ];
    __shared__ float  red[NT/64][NQ];

    const int tid = threadIdx.x;
    const int b   = blockIdx.x;

    // ---------------- precompute (verified r1-r11) ----------------
    if (tid < NL*NQ) {
        int l = tid / NQ, q = tid % NQ;
        float hx = 0.5f*prx[l*NQ+q], hy = 0.5f*pry[l*NQ+q], hz = 0.5f*prz[l*NQ+q];
        float cx = cosf(hx), sx = sinf(hx);
        float cy = cosf(hy), sy = sinf(hy);
        float cz = cosf(hz), sz = sinf(hz);
        c32 m00 = { cy*cx,  sy*sx };
        c32 m01 = {-sy*cx, -cy*sx };
        c32 m10 = { sy*cx, -cy*sx };
        c32 m11 = { cy*cx, -sy*sx };
        c32 e0 = {cz, -sz}, e1 = {cz, sz};
        c32 u00 = cmul(e0, m00), u01 = cmul(e0, m01);
        c32 u10 = cmul(e1, m10), u11 = cmul(e1, m11);
        float* U = Um[l][q];
        U[0]=u00.x; U[1]=u00.y; U[2]=u01.x; U[3]=u01.y;
        U[4]=u10.x; U[5]=u10.y; U[6]=u11.x; U[7]=u11.y;
    } else if (tid >= 64 && tid < 64 + NL*192) {
        int t2 = tid - 64;
        int l = t2 / 192, r = t2 % 192;
        if (r < 128) {                       // bit positions 0..6, theta 12-p
            float a = 0.f;
            for (int p = 0; p < 7; ++p) {
                float th = 0.5f * pent[l*(NQ-1) + (12 - p)];
                a += ((r >> p) & 1) ? th : -th;
            }
            tloc[l][r] = make_float2(cosf(a), sinf(a));
        } else {                             // positions 7..12, theta 5-p'
            int m = r - 128;
            float a = 0.f;
            for (int p = 0; p < 6; ++p) {
                float th = 0.5f * pent[l*(NQ-1) + (5 - p)];
                a += ((m >> p) & 1) ? th : -th;
            }
            thic[l][m] = make_float2(cosf(a), sinf(a));
        }
    } else if (tid >= 960 && tid < 960 + NQ) {
        int i = tid - 960;
        float th = tanhf(x[b*NQ + i]) * 3.14159265358979323846f;
        encc[i] = cosf(0.5f*th);
        encs[i] = sinf(0.5f*th);
    }
    __syncthreads();

    // ---- init = layer-0 "S1": product state + q1,q2,q3 in-register ----
    {
        float prodT = 1.f;
        #pragma unroll
        for (int p = 0; p < 10; ++p)         // y bit p <-> qubit 13-p
            prodT *= ((tid >> p) & 1) ? encs[13-p] : encc[13-p];
        #pragma unroll 1
        for (int h = 0; h < 2; ++h) {
            float ah = prodT * (h ? encs[0] : encc[0]);
            c32 v[8];
            #pragma unroll
            for (int m = 0; m < 8; ++m) {
                float a = ah
                        * ((m & 4) ? encs[1] : encc[1])
                        * ((m & 2) ? encs[2] : encc[2])
                        * ((m & 1) ? encs[3] : encc[3]);
                v[m] = { a, 0.f };
            }
            gate8(v, Um[0][1], 4);           // q1 at y bit 12 = m bit 2
            gate8(v, Um[0][2], 2);
            gate8(v, Um[0][3], 1);
            const int yb = (h << 13) | tid;
            #pragma unroll
            for (int m = 0; m < 8; ++m) st[yb + (m << 10)] = make_float2(v[m].x, v[m].y);
        }
    }
    __syncthreads();

    #pragma unroll 1
    for (int l = 0; l < NL; ++l) {
        // ---- S1 (l>=1): entangle(l-1) gather+phase fused with q1,q2,q3 ----
        if (l > 0) {
            #pragma unroll 1
            for (int h = 0; h < 2; ++h) {
                const int yb = (h << 13) | tid;
                c32 v[8];
                #pragma unroll
                for (int m = 0; m < 8; ++m) {
                    int y = yb + (m << 10);
                    int a = y ^ (y >> 1);    // gather source (verified r1-r11)
                    float2 f = st[a];
                    v[m] = phase_mul(tloc[l-1][y & 127], thic[l-1][(y >> 7) & 63], f);
                }
                gate8(v, Um[l][1], 4);       // q1 at y bit 12 = m bit 2
                gate8(v, Um[l][2], 2);
                gate8(v, Um[l][3], 1);
                __syncthreads();             // all reads of this half done
                #pragma unroll
                for (int m = 0; m < 8; ++m) st[yb + (m << 10)] = make_float2(v[m].x, v[m].y);
            }
            __syncthreads();
        }

        // ---- S2: q0,q4,q5 (bits 13,9,8); thread-exclusive tuples ----
        #pragma unroll 1
        for (int m = 0; m < 2; ++m) {
            const int T  = tid + (m << 10);
            const int ib = ((T >> 8) << 10) | (T & 255);
            c32 v[8];
            #pragma unroll
            for (int k = 0; k < 8; ++k) {
                int a = ib + ((k & 4) ? 8192 : 0) + ((k & 2) ? 512 : 0) + ((k & 1) ? 256 : 0);
                float2 f = st[a];
                v[k] = {f.x, f.y};
            }
            gate8(v, Um[l][0], 4);           // q0 at bit 13 = k bit 2
            gate8(v, Um[l][4], 2);           // q4 at bit 9
            gate8(v, Um[l][5], 1);           // q5 at bit 8
            #pragma unroll
            for (int k = 0; k < 8; ++k) {
                int a = ib + ((k & 4) ? 8192 : 0) + ((k & 2) ? 512 : 0) + ((k & 1) ? 256 : 0);
                st[a] = make_float2(v[k].x, v[k].y);
            }
        }
        __syncthreads();

        // ---- MEGA (wave-local, barrier-free): q6..q13.
        //      Wave w owns amps [w*1024, (w+1)*1024); gate bits 7..0 stay
        //      inside that region, and intra-wave LDS ops execute in program
        //      order -> no __syncthreads between the three sub-sweeps. ----
        {
            const int lane  = tid & 63;
            const int wbase = (tid >> 6) << 10;

            // M1: q6,q7,q8 (bits 7,6,5); lanes spread over bits 4..0 -> 2-way
            #pragma unroll 1
            for (int m = 0; m < 2; ++m) {
                const int t  = (m << 6) | lane;
                const int ib = wbase | ((t >> 5) << 8) | (t & 31);
                c32 v[8];
                #pragma unroll
                for (int k = 0; k < 8; ++k) { float2 f = st[ib + (k << 5)]; v[k] = {f.x, f.y}; }
                gate8(v, Um[l][6], 4);       // q6 at bit 7 = k bit 2
                gate8(v, Um[l][7], 2);
                gate8(v, Um[l][8], 1);
                #pragma unroll
                for (int k = 0; k < 8; ++k) st[ib + (k << 5)] = make_float2(v[k].x, v[k].y);
            }

            // M2: q9,q10,q11 (bits 4,3,2); bits 3,2 XOR-spread by lane (role swap)
            #pragma unroll 1
            for (int m = 0; m < 2; ++m) {
                const int t   = (m << 6) | lane;
                const int f5  = t >> 2;          // amp bits 9..5
                const int lo2 = t & 3;           // amp bits 1..0
                const int swz = f5 & 3;          // XOR on amp bits 3,2
                const int ib  = wbase | (f5 << 5) | lo2;
                c32 v[8]; int ad[8];
                #pragma unroll
                for (int k = 0; k < 8; ++k) {
                    ad[k] = ib | (((k & 3) ^ swz) << 2) | ((k >> 2) << 4);
                    float2 f = st[ad[k]];
                    v[k] = {f.x, f.y};
                }
                gate8(v, Um[l][9], 4);                      // q9 at bit 4 (not swizzled)
                gate8sw(v, Um[l][10], 2, (swz >> 1) & 1);   // q10 at bit 3
                gate8sw(v, Um[l][11], 1,  swz       & 1);   // q11 at bit 2
                #pragma unroll
                for (int k = 0; k < 8; ++k) st[ad[k]] = make_float2(v[k].x, v[k].y);
            }

            // M3: q12,q13 (bits 1,0); XOR-spread + role swap
            #pragma unroll 1
            for (int m = 0; m < 4; ++m) {
                const int t   = (m << 6) | lane;
                const int swz = t & 3;
                const int ib  = wbase | (t << 2);
                c32 v[4];
                #pragma unroll
                for (int k = 0; k < 4; ++k) { float2 f = st[ib | (k ^ swz)]; v[k] = {f.x, f.y}; }
                gate4sw(v, Um[l][12], 2, (swz >> 1) & 1);   // q12 at bit 1
                gate4sw(v, Um[l][13], 1,  swz       & 1);   // q13 at bit 0
                #pragma unroll
                for (int k = 0; k < 4; ++k) st[ib | (k ^ swz)] = make_float2(v[k].x, v[k].y);
            }
        }
        __syncthreads();
    }

    // ---- epilogue: entangle-3 (gather+phase) fused with <Z_i> ----
    float acc[NQ];
    #pragma unroll
    for (int i = 0; i < NQ; ++i) acc[i] = 0.f;
    #pragma unroll
    for (int j = 0; j < APT; ++j) {
        int y = tid + j*NT;
        int a = y ^ (y >> 1);
        float2 f = st[a];
        c32 r = phase_mul(tloc[NL-1][y & 127], thic[NL-1][(y >> 7) & 63], f);
        float pr = r.x*r.x + r.y*r.y;
        #pragma unroll
        for (int p = 0; p < NQ; ++p)         // qubit NQ-1-p at bit position p
            acc[NQ-1-p] += ((y >> p) & 1) ? -pr : pr;
    }
    #pragma unroll
    for (int off = 32; off >= 1; off >>= 1) {
        #pragma unroll
        for (int i = 0; i < NQ; ++i)
            acc[i] += __shfl_down(acc[i], off, 64);
    }
    const int wid = tid >> 6, lane = tid & 63;
    if (lane == 0) {
        #pragma unroll
        for (int i = 0; i < NQ; ++i) red[wid][i] = acc[i];
    }
    __syncthreads();
    if (tid < NQ) {
        float s = 0.f;
        #pragma unroll
        for (int w = 0; w < NT/64; ++w) s += red[w][tid];
        out[b*NQ + tid] = s;
    }
}

extern "C" void kernel_launch(void* const* d_in, const int* in_sizes, int n_in,
                              void* d_out, int out_size, void* d_ws, size_t ws_size,
                              hipStream_t stream) {
    (void)d_ws; (void)ws_size; (void)n_in; (void)out_size;
    const float* x    = (const float*)d_in[0];
    const float* prx  = (const float*)d_in[1];
    const float* pry  = (const float*)d_in[2];
    const float* prz  = (const float*)d_in[3];
    const float* pent = (const float*)d_in[4];
    float* out = (float*)d_out;
    const int B = in_sizes[0] / NQ;
    qc_kernel<<<B, NT, 0, stream>>>(x, prx, pry, prz, pent, out);
}

// Round 13
// 135.057 us; speedup vs baseline: 1.0003x; 1.0003x over previous
//
#include <hip/hip_runtime.h>
#include <math.h>

#define NQ 14
#define NL 4
#define NS (1 << NQ)      // 16384 amplitudes
#define NT 1024           // threads (fallback kernel)
#define APT (NS / NT)
#define NT5 512           // threads (wide-register kernel)

struct c32 { float x, y; };
__device__ __forceinline__ c32 cmul(c32 a, c32 b) { return {a.x*b.x - a.y*b.y, a.x*b.y + a.y*b.x}; }
__device__ __forceinline__ c32 cadd(c32 a, c32 b) { return {a.x + b.x, a.y + b.y}; }

__device__ __forceinline__ c32 phase_mul(float2 p1, float2 p2, float2 f) {
    c32 ph = { p1.x*p2.x - p1.y*p2.y, p1.x*p2.y + p1.y*p2.x };
    return { ph.x*f.x - ph.y*f.y, ph.x*f.y + ph.y*f.x };
}

__device__ __forceinline__ void gate8(c32* v, const float* U, const int s) {
    float4 u0 = *(const float4*)U;
    float4 u1 = *(const float4*)(U + 4);
    c32 a00={u0.x,u0.y}, a01={u0.z,u0.w}, a10={u1.x,u1.y}, a11={u1.z,u1.w};
    #pragma unroll
    for (int k = 0; k < 8; ++k) {
        if (k & s) continue;
        c32 A = v[k], B = v[k | s];
        v[k]     = cadd(cmul(a00, A), cmul(a01, B));
        v[k | s] = cadd(cmul(a10, A), cmul(a11, B));
    }
}

__device__ __forceinline__ void gate16(c32* v, const float* U, const int s) {
    float4 u0 = *(const float4*)U;
    float4 u1 = *(const float4*)(U + 4);
    c32 a00={u0.x,u0.y}, a01={u0.z,u0.w}, a10={u1.x,u1.y}, a11={u1.z,u1.w};
    #pragma unroll
    for (int k = 0; k < 16; ++k) {
        if (k & s) continue;
        c32 A = v[k], B = v[k | s];
        v[k]     = cadd(cmul(a00, A), cmul(a01, B));
        v[k | s] = cadd(cmul(a10, A), cmul(a11, B));
    }
}

// Slot k holds logical element k^swbits: role-swap U'[i][j]=U[i^sw][j^sw]
__device__ __forceinline__ void gate8sw(c32* v, const float* U, const int s, const int sw) {
    float4 u0 = *(const float4*)U;
    float4 u1 = *(const float4*)(U + 4);
    c32 n00={u0.x,u0.y}, n01={u0.z,u0.w}, n10={u1.x,u1.y}, n11={u1.z,u1.w};
    c32 a00 = sw ? n11 : n00;
    c32 a01 = sw ? n10 : n01;
    c32 a10 = sw ? n01 : n10;
    c32 a11 = sw ? n00 : n11;
    #pragma unroll
    for (int k = 0; k < 8; ++k) {
        if (k & s) continue;
        c32 A = v[k], B = v[k | s];
        v[k]     = cadd(cmul(a00, A), cmul(a01, B));
        v[k | s] = cadd(cmul(a10, A), cmul(a11, B));
    }
}

__device__ __forceinline__ void gate4sw(c32* v, const float* U, const int s, const int sw) {
    float4 u0 = *(const float4*)U;
    float4 u1 = *(const float4*)(U + 4);
    c32 n00={u0.x,u0.y}, n01={u0.z,u0.w}, n10={u1.x,u1.y}, n11={u1.z,u1.w};
    c32 a00 = sw ? n11 : n00;
    c32 a01 = sw ? n10 : n01;
    c32 a10 = sw ? n01 : n10;
    c32 a11 = sw ? n00 : n11;
    #pragma unroll
    for (int k = 0; k < 4; ++k) {
        if (k & s) continue;
        c32 A = v[k], B = v[k | s];
        v[k]     = cadd(cmul(a00, A), cmul(a01, B));
        v[k | s] = cadd(cmul(a10, A), cmul(a11, B));
    }
}

// ===========================================================================
// qc512 — 512 threads, 32 amps/thread, v[16] tuples (needs >64 VGPRs;
// host checks localSizeBytes and falls back to qc1024 if the compiler
// spilled). waves_per_eu(2,2): 8 waves/block = exactly 2/EU -> 256-reg budget.
// ===========================================================================
__global__ __launch_bounds__(NT5) __attribute__((amdgpu_waves_per_eu(2, 2)))
void qc512(const float* __restrict__ x,
           const float* __restrict__ prx,
           const float* __restrict__ pry,
           const float* __restrict__ prz,
           const float* __restrict__ pent,
           float* __restrict__ out)
{
    __shared__ __align__(16) float2 st[NS];   // 128 KB state, natural order
    __shared__ float  Um[NL][NQ][8];
    __shared__ float2 tloc[NL][128];
    __shared__ float2 thic[NL][64];
    __shared__ float  encc[NQ], encs[NQ];
    __shared__ float  red[NT5/64][NQ];

    const int tid = threadIdx.x;
    const int b   = blockIdx.x;
    float4* st4 = reinterpret_cast<float4*>(st);   // pair of amps per float4

    // ---------------- precompute ----------------
    if (tid < NL*NQ) {
        int l = tid / NQ, q = tid % NQ;
        float hx = 0.5f*prx[l*NQ+q], hy = 0.5f*pry[l*NQ+q], hz = 0.5f*prz[l*NQ+q];
        float cx = cosf(hx), sx = sinf(hx);
        float cy = cosf(hy), sy = sinf(hy);
        float cz = cosf(hz), sz = sinf(hz);
        c32 m00 = { cy*cx,  sy*sx };
        c32 m01 = {-sy*cx, -cy*sx };
        c32 m10 = { sy*cx, -cy*sx };
        c32 m11 = { cy*cx, -sy*sx };
        c32 e0 = {cz, -sz}, e1 = {cz, sz};
        c32 u00 = cmul(e0, m00), u01 = cmul(e0, m01);
        c32 u10 = cmul(e1, m10), u11 = cmul(e1, m11);
        float* U = Um[l][q];
        U[0]=u00.x; U[1]=u00.y; U[2]=u01.x; U[3]=u01.y;
        U[4]=u10.x; U[5]=u10.y; U[6]=u11.x; U[7]=u11.y;
    }
    for (int e = tid; e < NL*192; e += NT5) {
        int l = e / 192, r = e % 192;
        if (r < 128) {
            float a = 0.f;
            for (int p = 0; p < 7; ++p) {
                float th = 0.5f * pent[l*(NQ-1) + (12 - p)];
                a += ((r >> p) & 1) ? th : -th;
            }
            tloc[l][r] = make_float2(cosf(a), sinf(a));
        } else {
            int m = r - 128;
            float a = 0.f;
            for (int p = 0; p < 6; ++p) {
                float th = 0.5f * pent[l*(NQ-1) + (5 - p)];
                a += ((m >> p) & 1) ? th : -th;
            }
            thic[l][m] = make_float2(cosf(a), sinf(a));
        }
    }
    if (tid >= 480 && tid < 480 + NQ) {
        int i = tid - 480;
        float th = tanhf(x[b*NQ + i]) * 3.14159265358979323846f;
        encc[i] = cosf(0.5f*th);
        encs[i] = sinf(0.5f*th);
    }
    __syncthreads();

    // ---- init = layer-0 S1: product state + q1,q2,q3 in-register.
    //      y = (h<<13)|(k<<10)|(tid<<1)|p; slot = (k<<1)|p. ----
    {
        float prodT = 1.f;
        #pragma unroll
        for (int bb = 0; bb < 9; ++bb)       // tid bit bb <-> y bit bb+1 <-> qubit 12-bb
            prodT *= ((tid >> bb) & 1) ? encs[12-bb] : encc[12-bb];
        #pragma unroll 1
        for (int h = 0; h < 2; ++h) {
            float ah = prodT * (h ? encs[0] : encc[0]);
            c32 v[16];
            #pragma unroll
            for (int k = 0; k < 8; ++k) {
                float kf = ((k & 4) ? encs[1] : encc[1])
                         * ((k & 2) ? encs[2] : encc[2])
                         * ((k & 1) ? encs[3] : encc[3]);
                v[(k<<1)]   = { ah * kf * encc[13], 0.f };
                v[(k<<1)|1] = { ah * kf * encs[13], 0.f };
            }
            gate16(v, Um[0][1], 8);          // q1 at y bit 12 = slot bit 3
            gate16(v, Um[0][2], 4);
            gate16(v, Um[0][3], 2);
            #pragma unroll
            for (int k = 0; k < 8; ++k)
                st4[(h<<12) | (k<<9) | tid] =
                    make_float4(v[(k<<1)].x, v[(k<<1)].y, v[(k<<1)|1].x, v[(k<<1)|1].y);
        }
    }
    __syncthreads();

    #pragma unroll 1
    for (int l = 0; l < NL; ++l) {
        // ---- S1 (l>=1): entangle(l-1) gather+phase + q1,q2,q3.
        //      Sources for pair (p=0,1) are {x0, x0^1} = one aligned float4;
        //      swap = tid&1 (thread-uniform). Gray preserves bit 13 ->
        //      half-sweeps with read/write barrier each. ----
        if (l > 0) {
            const int swp = tid & 1;
            #pragma unroll 1
            for (int h = 0; h < 2; ++h) {
                c32 v[16];
                #pragma unroll
                for (int k = 0; k < 8; ++k) {
                    int y0 = (h<<13) | (k<<10) | (tid<<1);
                    int x0 = y0 ^ (y0 >> 1);
                    float4 q = st4[x0 >> 1];
                    float2 s0 = swp ? make_float2(q.z, q.w) : make_float2(q.x, q.y);
                    float2 s1 = swp ? make_float2(q.x, q.y) : make_float2(q.z, q.w);
                    int y1 = y0 | 1;
                    v[(k<<1)]   = phase_mul(tloc[l-1][y0 & 127], thic[l-1][(y0 >> 7) & 63], s0);
                    v[(k<<1)|1] = phase_mul(tloc[l-1][y1 & 127], thic[l-1][(y1 >> 7) & 63], s1);
                }
                gate16(v, Um[l][1], 8);
                gate16(v, Um[l][2], 4);
                gate16(v, Um[l][3], 2);
                __syncthreads();             // all reads of this half done
                #pragma unroll
                for (int k = 0; k < 8; ++k)
                    st4[(h<<12) | (k<<9) | tid] =
                        make_float4(v[(k<<1)].x, v[(k<<1)].y, v[(k<<1)|1].x, v[(k<<1)|1].y);
            }
            __syncthreads();
        }

        // ---- S2: q0,q4,q5 (bits 13,9,8); slot=(k<<1)|p, pair in float4 ----
        #pragma unroll 1
        for (int m = 0; m < 2; ++m) {
            const int u = (m << 9) | tid;    // 10 bits -> y bits 12..10, 7..1
            const int fb = ((u >> 7) << 9) | (u & 127);
            c32 v[16];
            #pragma unroll
            for (int k = 0; k < 8; ++k) {
                int fidx = fb | ((k & 4) ? 4096 : 0) | ((k & 2) ? 256 : 0) | ((k & 1) ? 128 : 0);
                float4 q = st4[fidx];
                v[(k<<1)]   = { q.x, q.y };
                v[(k<<1)|1] = { q.z, q.w };
            }
            gate16(v, Um[l][0], 8);          // q0 at bit 13 = slot bit 3
            gate16(v, Um[l][4], 4);          // q4 at bit 9
            gate16(v, Um[l][5], 2);          // q5 at bit 8
            #pragma unroll
            for (int k = 0; k < 8; ++k) {
                int fidx = fb | ((k & 4) ? 4096 : 0) | ((k & 2) ? 256 : 0) | ((k & 1) ? 128 : 0);
                st4[fidx] = make_float4(v[(k<<1)].x, v[(k<<1)].y, v[(k<<1)|1].x, v[(k<<1)|1].y);
            }
        }
        __syncthreads();

        // ---- S3: q6,q7,q8 (bits 7,6,5) ----
        #pragma unroll 1
        for (int m = 0; m < 2; ++m) {
            const int u = (m << 9) | tid;    // y bits 13..8, 4..1
            const int fb = ((u >> 4) << 7) | (u & 15);
            c32 v[16];
            #pragma unroll
            for (int k = 0; k < 8; ++k) {
                float4 q = st4[fb | (k << 4)];
                v[(k<<1)]   = { q.x, q.y };
                v[(k<<1)|1] = { q.z, q.w };
            }
            gate16(v, Um[l][6], 8);          // q6 at bit 7 = slot bit 3
            gate16(v, Um[l][7], 4);
            gate16(v, Um[l][8], 2);
            #pragma unroll
            for (int k = 0; k < 8; ++k)
                st4[fb | (k << 4)] = make_float4(v[(k<<1)].x, v[(k<<1)].y, v[(k<<1)|1].x, v[(k<<1)|1].y);
        }
        __syncthreads();

        // ---- S4+S5: own 32 amps (base = tid<<5), b64 XOR order (x5) +
        //      role-swapped gates; no barriers inside (exclusive + in-order) ----
        {
            const int x5   = tid & 31;
            const int base = tid << 5;
            // S4: q9,q10 (element bits 4,3)
            #pragma unroll 1
            for (int g = 0; g < 8; ++g) {    // element bits 2..0
                c32 v[4];
                #pragma unroll
                for (int k = 0; k < 4; ++k) {
                    float2 f = st[base | (((k << 3) | g) ^ x5)];
                    v[k] = {f.x, f.y};
                }
                gate4sw(v, Um[l][9],  2, (x5 >> 4) & 1);  // q9 at e-bit 4 = slot bit 1
                gate4sw(v, Um[l][10], 1, (x5 >> 3) & 1);  // q10 at e-bit 3
                #pragma unroll
                for (int k = 0; k < 4; ++k)
                    st[base | (((k << 3) | g) ^ x5)] = make_float2(v[k].x, v[k].y);
            }
            // S5: q11,q12,q13 (element bits 2..0)
            #pragma unroll 1
            for (int g2 = 0; g2 < 4; ++g2) { // element bits 4,3
                c32 v[8];
                #pragma unroll
                for (int s = 0; s < 8; ++s) {
                    float2 f = st[base | (((g2 << 3) | s) ^ x5)];
                    v[s] = {f.x, f.y};
                }
                gate8sw(v, Um[l][11], 4, (x5 >> 2) & 1);
                gate8sw(v, Um[l][12], 2, (x5 >> 1) & 1);
                gate8sw(v, Um[l][13], 1,  x5       & 1);
                #pragma unroll
                for (int s = 0; s < 8; ++s)
                    st[base | (((g2 << 3) | s) ^ x5)] = make_float2(v[s].x, v[s].y);
            }
        }
        __syncthreads();
    }

    // ---- epilogue: entangle-3 gather+phase fused with <Z_i> ----
    float acc[NQ];
    #pragma unroll
    for (int i = 0; i < NQ; ++i) acc[i] = 0.f;
    #pragma unroll
    for (int j = 0; j < 32; ++j) {
        int y = tid + (j << 9);
        int a = y ^ (y >> 1);
        float2 f = st[a];
        c32 r = phase_mul(tloc[NL-1][y & 127], thic[NL-1][(y >> 7) & 63], f);
        float pr = r.x*r.x + r.y*r.y;
        #pragma unroll
        for (int p = 0; p < NQ; ++p)
            acc[NQ-1-p] += ((y >> p) & 1) ? -pr : pr;
    }
    #pragma unroll
    for (int off = 32; off >= 1; off >>= 1) {
        #pragma unroll
        for (int i = 0; i < NQ; ++i)
            acc[i] += __shfl_down(acc[i], off, 64);
    }
    const int wid = tid >> 6, lane = tid & 63;
    if (lane == 0) {
        #pragma unroll
        for (int i = 0; i < NQ; ++i) red[wid][i] = acc[i];
    }
    __syncthreads();
    if (tid < NQ) {
        float s = 0.f;
        #pragma unroll
        for (int w = 0; w < NT5/64; ++w) s += red[w][tid];
        out[b*NQ + tid] = s;
    }
}

// ===========================================================================
// qc1024 — r11 kernel verbatim (verified: 84 µs prof, absmax 3e-5). Fallback.
// ===========================================================================
__global__ __launch_bounds__(NT) __attribute__((amdgpu_waves_per_eu(4, 4)))
void qc1024(const float* __restrict__ x,
            const float* __restrict__ prx,
            const float* __restrict__ pry,
            const float* __restrict__ prz,
            const float* __restrict__ pent,
            float* __restrict__ out)
{
    __shared__ float2 st[NS];
    __shared__ float  Um[NL][NQ][8];
    __shared__ float2 tloc[NL][128];
    __shared__ float2 thic[NL][64];
    __shared__ float  encc[NQ], encs[NQ];
    __shared__ float  red[NT/64][NQ];

    const int tid = threadIdx.x;
    const int b   = blockIdx.x;

    if (tid < NL*NQ) {
        int l = tid / NQ, q = tid % NQ;
        float hx = 0.5f*prx[l*NQ+q], hy = 0.5f*pry[l*NQ+q], hz = 0.5f*prz[l*NQ+q];
        float cx = cosf(hx), sx = sinf(hx);
        float cy = cosf(hy), sy = sinf(hy);
        float cz = cosf(hz), sz = sinf(hz);
        c32 m00 = { cy*cx,  sy*sx };
        c32 m01 = {-sy*cx, -cy*sx };
        c32 m10 = { sy*cx, -cy*sx };
        c32 m11 = { cy*cx, -sy*sx };
        c32 e0 = {cz, -sz}, e1 = {cz, sz};
        c32 u00 = cmul(e0, m00), u01 = cmul(e0, m01);
        c32 u10 = cmul(e1, m10), u11 = cmul(e1, m11);
        float* U = Um[l][q];
        U[0]=u00.x; U[1]=u00.y; U[2]=u01.x; U[3]=u01.y;
        U[4]=u10.x; U[5]=u10.y; U[6]=u11.x; U[7]=u11.y;
    } else if (tid >= 64 && tid < 64 + NL*192) {
        int t2 = tid - 64;
        int l = t2 / 192, r = t2 % 192;
        if (r < 128) {
            float a = 0.f;
            for (int p = 0; p < 7; ++p) {
                float th = 0.5f * pent[l*(NQ-1) + (12 - p)];
                a += ((r >> p) & 1) ? th : -th;
            }
            tloc[l][r] = make_float2(cosf(a), sinf(a));
        } else {
            int m = r - 128;
            float a = 0.f;
            for (int p = 0; p < 6; ++p) {
                float th = 0.5f * pent[l*(NQ-1) + (5 - p)];
                a += ((m >> p) & 1) ? th : -th;
            }
            thic[l][m] = make_float2(cosf(a), sinf(a));
        }
    } else if (tid >= 960 && tid < 960 + NQ) {
        int i = tid - 960;
        float th = tanhf(x[b*NQ + i]) * 3.14159265358979323846f;
        encc[i] = cosf(0.5f*th);
        encs[i] = sinf(0.5f*th);
    }
    __syncthreads();

    {
        float prodT = 1.f;
        #pragma unroll
        for (int p = 0; p < 10; ++p)
            prodT *= ((tid >> p) & 1) ? encs[13-p] : encc[13-p];
        #pragma unroll 1
        for (int h = 0; h < 2; ++h) {
            float ah = prodT * (h ? encs[0] : encc[0]);
            c32 v[8];
            #pragma unroll
            for (int m = 0; m < 8; ++m) {
                float a = ah
                        * ((m & 4) ? encs[1] : encc[1])
                        * ((m & 2) ? encs[2] : encc[2])
                        * ((m & 1) ? encs[3] : encc[3]);
                v[m] = { a, 0.f };
            }
            gate8(v, Um[0][1], 4);
            gate8(v, Um[0][2], 2);
            gate8(v, Um[0][3], 1);
            const int yb = (h << 13) | tid;
            #pragma unroll
            for (int m = 0; m < 8; ++m) st[yb + (m << 10)] = make_float2(v[m].x, v[m].y);
        }
    }
    __syncthreads();

    #pragma unroll 1
    for (int l = 0; l < NL; ++l) {
        if (l > 0) {
            #pragma unroll 1
            for (int h = 0; h < 2; ++h) {
                const int yb = (h << 13) | tid;
                c32 v[8];
                #pragma unroll
                for (int m = 0; m < 8; ++m) {
                    int y = yb + (m << 10);
                    int a = y ^ (y >> 1);
                    float2 f = st[a];
                    v[m] = phase_mul(tloc[l-1][y & 127], thic[l-1][(y >> 7) & 63], f);
                }
                gate8(v, Um[l][1], 4);
                gate8(v, Um[l][2], 2);
                gate8(v, Um[l][3], 1);
                __syncthreads();
                #pragma unroll
                for (int m = 0; m < 8; ++m) st[yb + (m << 10)] = make_float2(v[m].x, v[m].y);
            }
            __syncthreads();
        }

        #pragma unroll 1
        for (int m = 0; m < 2; ++m) {
            const int T  = tid + (m << 10);
            const int ib = ((T >> 8) << 10) | (T & 255);
            c32 v[8];
            #pragma unroll
            for (int k = 0; k < 8; ++k) {
                int a = ib + ((k & 4) ? 8192 : 0) + ((k & 2) ? 512 : 0) + ((k & 1) ? 256 : 0);
                float2 f = st[a];
                v[k] = {f.x, f.y};
            }
            gate8(v, Um[l][0], 4);
            gate8(v, Um[l][4], 2);
            gate8(v, Um[l][5], 1);
            #pragma unroll
            for (int k = 0; k < 8; ++k) {
                int a = ib + ((k & 4) ? 8192 : 0) + ((k & 2) ? 512 : 0) + ((k & 1) ? 256 : 0);
                st[a] = make_float2(v[k].x, v[k].y);
            }
        }
        __syncthreads();

        #pragma unroll 1
        for (int m = 0; m < 2; ++m) {
            const int T  = tid + (m << 10);
            const int ib = ((T >> 5) << 8) | (T & 31);
            c32 v[8];
            #pragma unroll
            for (int k = 0; k < 8; ++k) { float2 f = st[ib + (k << 5)]; v[k] = {f.x, f.y}; }
            gate8(v, Um[l][6], 4);
            gate8(v, Um[l][7], 2);
            gate8(v, Um[l][8], 1);
            #pragma unroll
            for (int k = 0; k < 8; ++k) st[ib + (k << 5)] = make_float2(v[k].x, v[k].y);
        }
        __syncthreads();

        #pragma unroll 1
        for (int m = 0; m < 4; ++m) {
            const int T  = tid + (m << 10);
            const int ib = ((T >> 3) << 5) | (T & 7);
            c32 v[4];
            #pragma unroll
            for (int k = 0; k < 4; ++k) { float2 f = st[ib + (k << 3)]; v[k] = {f.x, f.y}; }
            gate4sw(v, Um[l][9], 2, 0);
            gate4sw(v, Um[l][10], 1, 0);
            #pragma unroll
            for (int k = 0; k < 4; ++k) st[ib + (k << 3)] = make_float2(v[k].x, v[k].y);
        }
        __syncthreads();

        {
            const int t4   = tid & 15;
            const int base = tid << 4;
            #pragma unroll 1
            for (int m = 0; m < 2; ++m) {
                c32 v[8];
                #pragma unroll
                for (int s = 0; s < 8; ++s) {
                    float2 f = st[base | (((m << 3) | s) ^ t4)];
                    v[s] = {f.x, f.y};
                }
                gate8sw(v, Um[l][11], 4, (t4 >> 2) & 1);
                gate8sw(v, Um[l][12], 2, (t4 >> 1) & 1);
                gate8sw(v, Um[l][13], 1,  t4       & 1);
                #pragma unroll
                for (int s = 0; s < 8; ++s)
                    st[base | (((m << 3) | s) ^ t4)] = make_float2(v[s].x, v[s].y);
            }
        }
        __syncthreads();
    }

    float acc[NQ];
    #pragma unroll
    for (int i = 0; i < NQ; ++i) acc[i] = 0.f;
    #pragma unroll
    for (int j = 0; j < APT; ++j) {
        int y = tid + j*NT;
        int a = y ^ (y >> 1);
        float2 f = st[a];
        c32 r = phase_mul(tloc[NL-1][y & 127], thic[NL-1][(y >> 7) & 63], f);
        float pr = r.x*r.x + r.y*r.y;
        #pragma unroll
        for (int p = 0; p < NQ; ++p)
            acc[NQ-1-p] += ((y >> p) & 1) ? -pr : pr;
    }
    #pragma unroll
    for (int off = 32; off >= 1; off >>= 1) {
        #pragma unroll
        for (int i = 0; i < NQ; ++i)
            acc[i] += __shfl_down(acc[i], off, 64);
    }
    const int wid = tid >> 6, lane = tid & 63;
    if (lane == 0) {
        #pragma unroll
        for (int i = 0; i < NQ; ++i) red[wid][i] = acc[i];
    }
    __syncthreads();
    if (tid < NQ) {
        float s = 0.f;
        #pragma unroll
        for (int w = 0; w < NT/64; ++w) s += red[w][tid];
        out[b*NQ + tid] = s;
    }
}

extern "C" void kernel_launch(void* const* d_in, const int* in_sizes, int n_in,
                              void* d_out, int out_size, void* d_ws, size_t ws_size,
                              hipStream_t stream) {
    (void)d_ws; (void)ws_size; (void)n_in; (void)out_size;
    const float* x    = (const float*)d_in[0];
    const float* prx  = (const float*)d_in[1];
    const float* pry  = (const float*)d_in[2];
    const float* prz  = (const float*)d_in[3];
    const float* pent = (const float*)d_in[4];
    float* out = (float*)d_out;
    const int B = in_sizes[0] / NQ;

    // Host-side, capture-safe query: use the wide-register kernel only if the
    // compiler actually granted enough VGPRs (no scratch spill).
    static int use512 = -1;                    // resolved once; same every call
    if (use512 < 0) {
        hipFuncAttributes attr;
        hipError_t err = hipFuncGetAttributes(&attr, (const void*)qc512);
        use512 = (err == hipSuccess && attr.localSizeBytes == 0) ? 1 : 0;
    }
    if (use512)
        qc512<<<B, NT5, 0, stream>>>(x, prx, pry, prz, pent, out);
    else
        qc1024<<<B, NT, 0, stream>>>(x, prx, pry, prz, pent, out);
}